// Round 5
// baseline (277.098 us; speedup 1.0000x reference)
//
#include <hip/hip_runtime.h>
#include <math.h>

#define S_LEN 2048
#define NH 16
#define HD 64
#define DMODEL 1024
#define BATCH 4
#define M_TOT (BATCH * S_LEN)   // 8192

typedef __attribute__((ext_vector_type(8))) short bf16x8;
typedef __attribute__((ext_vector_type(4))) float f32x4;

#define CK 0.18033688f   // (1/sqrt(64)) * log2(e), folded into Q at projection

__device__ __forceinline__ unsigned short f2bf_rne(float f) {
    unsigned u = __float_as_uint(f);
    u += 0x7fffu + ((u >> 16) & 1u);
    return (unsigned short)(u >> 16);
}

__device__ __forceinline__ void gld16(unsigned short* lds, const unsigned short* g) {
    __builtin_amdgcn_global_load_lds(
        (const __attribute__((address_space(1))) void*)g,
        (__attribute__((address_space(3))) void*)lds, 16, 0, 0);
}

// ---------------------------------------------------------------------------
// cvt_fused: one dispatch for all input conversion.
// z=0..2: Wq/Wk/Wv [k][n] fp32 -> WT [n][k] bf16 (64x64 transpose tiles)
// z=3:    Wf (1024x64) -> WfT [64][1024]   (only blockIdx.x==0 active)
// z=4:    x fp32 -> bf16 (256 blocks x 32 float4/thread)
// ---------------------------------------------------------------------------
__global__ __launch_bounds__(256) void cvt_fused(
    const float* __restrict__ x,
    const float* __restrict__ Wq, const float* __restrict__ Wk,
    const float* __restrict__ Wv, const float* __restrict__ Wf,
    unsigned short* __restrict__ xb, unsigned short* __restrict__ WT)
{
    const int z = blockIdx.z;
    const int tid = threadIdx.x;

    if (z < 4) {
        if (z == 3 && blockIdx.x > 0) return;
        const float* W = (z == 0) ? Wq : (z == 1) ? Wk : (z == 2) ? Wv : Wf;
        const int ncol = (z == 3) ? 64 : DMODEL;
        unsigned short* out = WT + (size_t)z * DMODEL * DMODEL;

        __shared__ float Lt[64][65];
        const int r0 = blockIdx.y * 64;
        const int c0 = blockIdx.x * 64;

        #pragma unroll
        for (int p = 0; p < 4; p++) {
            int row = (tid >> 4) + p * 16;
            int c4 = (tid & 15) * 4;
            float4 v = *(const float4*)(W + (size_t)(r0 + row) * ncol + c0 + c4);
            Lt[row][c4 + 0] = v.x; Lt[row][c4 + 1] = v.y;
            Lt[row][c4 + 2] = v.z; Lt[row][c4 + 3] = v.w;
        }
        __syncthreads();
        #pragma unroll
        for (int p = 0; p < 4; p++) {
            int nr = (tid >> 4) + p * 16;
            int kc = (tid & 15) * 4;
            unsigned short t[4];
            #pragma unroll
            for (int j = 0; j < 4; j++) t[j] = f2bf_rne(Lt[kc + j][nr]);
            *(uint2*)(out + (size_t)(c0 + nr) * DMODEL + r0 + kc) = *(uint2*)t;
        }
    } else {
        const int gtid = (blockIdx.y * 16 + blockIdx.x) * 256 + tid;
        #pragma unroll
        for (int it = 0; it < 8; it++) {
            #pragma unroll
            for (int k = 0; k < 4; k++) {
                size_t i = ((size_t)((it * 4 + k) * 65536) + gtid) * 4;
                float4 v = *(const float4*)(x + i);
                unsigned short t[4];
                t[0] = f2bf_rne(v.x); t[1] = f2bf_rne(v.y);
                t[2] = f2bf_rne(v.z); t[3] = f2bf_rne(v.w);
                *(uint2*)(xb + i) = *(uint2*)t;
            }
        }
    }
}

// ---------------------------------------------------------------------------
// Kernel 1 (R17): FUSED QKV projection, SINGLE-BUFFERED for occupancy.
//   R4 post-mortem: the dbuf's 112 KB LDS forced 1 block/CU -- all 8 waves
//   in ONE barrier domain, so every drain idles the CU (MfmaUtil stuck 22%).
//   m132/m114: for the 2-barrier structure, resident-block count is the
//   dominant lever (3->2 blocks = 874->508 TF).  Single 56 KB buffer ->
//   2 independent blocks/CU, whole 512-block grid co-resident, 16 waves/CU;
//   one block's compute covers the other's drain.  R1 showed dbuf-vs-single
//   is null at fixed occupancy, so dropping it costs nothing.
//   Chunk layout / fragment reads / operand order / epilogues unchanged
//   from the R4-verified kernel.
// ---------------------------------------------------------------------------
__global__ __launch_bounds__(512) void qkv_fused_mfma(
    const unsigned short* __restrict__ xb,
    const unsigned short* __restrict__ WT,
    const float* __restrict__ bq, const float* __restrict__ bk,
    const float* __restrict__ bv,
    unsigned short* __restrict__ Qb, unsigned short* __restrict__ Kb,
    unsigned short* __restrict__ Vtb)
{
    __shared__ __align__(16) unsigned short Ws[24 * 512];   // 24 KB
    __shared__ __align__(16) unsigned short Bs[32 * 512];   // 32 KB

    const int lin = blockIdx.x;          // 0..511
    const int xcd = lin & 7;
    const int s   = lin >> 3;            // 0..63
    const int rb  = xcd * 4 + (s & 3);   // 0..31  (256-row tiles)
    const int ocb = s >> 2;              // 0..15  (64-oc tiles)

    const int tid = threadIdx.x;
    const int lane = tid & 63, w = tid >> 6;        // w 0..7
    const int quad = lane >> 4, l15 = lane & 15;

    const int R0  = rb * 256;
    const int OC0 = ocb * 64;

    const unsigned short* gW0 = WT +
        (size_t)(OC0 + (w >> 1) * 16 + l15) * DMODEL + (w & 1) * 32 + quad * 8;
    const unsigned short* gW1 = gW0 + (size_t)DMODEL * DMODEL;
    const unsigned short* gW2 = gW1 + (size_t)DMODEL * DMODEL;
    const unsigned short* gB0 = xb + (size_t)(R0 + w * 16 + l15) * DMODEL + quad * 8;
    const unsigned short* gB1 = gB0 + (size_t)128 * DMODEL;

    f32x4 acc[3][4][2];
    #pragma unroll
    for (int z = 0; z < 3; z++)
        #pragma unroll
        for (int i = 0; i < 4; i++)
            #pragma unroll
            for (int j = 0; j < 2; j++)
                #pragma unroll
                for (int c = 0; c < 4; c++) acc[z][i][j][c] = 0.f;

#define QKV_STAGE(K)  do {                                             \
        gld16(Ws + (0 * 8 + w) * 512, gW0 + (K));                      \
        gld16(Ws + (1 * 8 + w) * 512, gW1 + (K));                      \
        gld16(Ws + (2 * 8 + w) * 512, gW2 + (K));                      \
        gld16(Bs + ((w + 0) * 2 + 0) * 512, gB0 + (K));                \
        gld16(Bs + ((w + 0) * 2 + 1) * 512, gB0 + (K) + 32);           \
        gld16(Bs + ((w + 8) * 2 + 0) * 512, gB1 + (K));                \
        gld16(Bs + ((w + 8) * 2 + 1) * 512, gB1 + (K) + 32);           \
    } while (0)

    for (int t = 0; t < 16; ++t) {
        __syncthreads();          // previous compute done: buffer reusable
        QKV_STAGE(t * 64);
        __syncthreads();          // stage(t) landed (drain)

        #pragma unroll
        for (int sl = 0; sl < 2; sl++) {
            bf16x8 bfr[2];
            #pragma unroll
            for (int j = 0; j < 2; j++)
                bfr[j] = *(const bf16x8*)&Bs[((2 * w + j) * 2 + sl) * 512 + lane * 8];
            #pragma unroll
            for (int z = 0; z < 3; z++) {
                bf16x8 af[4];
                #pragma unroll
                for (int i = 0; i < 4; i++)
                    af[i] = *(const bf16x8*)&Ws[(z * 8 + i * 2 + sl) * 512 + lane * 8];
                if (z != 2) {
                    #pragma unroll
                    for (int i = 0; i < 4; i++)
                        #pragma unroll
                        for (int j = 0; j < 2; j++)
                            acc[z][i][j] = __builtin_amdgcn_mfma_f32_16x16x32_bf16(
                                af[i], bfr[j], acc[z][i][j], 0, 0, 0);
                } else {
                    #pragma unroll
                    for (int i = 0; i < 4; i++)
                        #pragma unroll
                        for (int j = 0; j < 2; j++)
                            acc[2][i][j] = __builtin_amdgcn_mfma_f32_16x16x32_bf16(
                                bfr[j], af[i], acc[2][i][j], 0, 0, 0);
                }
            }
        }
    }
#undef QKV_STAGE

    #pragma unroll
    for (int z = 0; z < 2; z++) {
        unsigned short* out = (z == 0) ? Qb : Kb;
        const float* bias = (z == 0) ? bq : bk;
        const float qs = (z == 0) ? CK : 1.0f;
        #pragma unroll
        for (int i = 0; i < 4; i++) {
            int oc = OC0 + i * 16 + quad * 4;
            float4 bv4 = *(const float4*)&bias[oc];
            #pragma unroll
            for (int j = 0; j < 2; j++) {
                int row = R0 + w * 32 + j * 16 + l15;
                unsigned short t4[4];
                t4[0] = f2bf_rne((acc[z][i][j][0] + bv4.x) * qs);
                t4[1] = f2bf_rne((acc[z][i][j][1] + bv4.y) * qs);
                t4[2] = f2bf_rne((acc[z][i][j][2] + bv4.z) * qs);
                t4[3] = f2bf_rne((acc[z][i][j][3] + bv4.w) * qs);
                *(uint2*)(out + (size_t)row * DMODEL + oc) = *(uint2*)t4;
            }
        }
    }
    {
        const int b = R0 >> 11;
        const int sbase = (R0 & 2047) + w * 32;
        #pragma unroll
        for (int i = 0; i < 4; i++) {
            int oc = OC0 + i * 16 + l15;
            float bvv = bv[oc];
            #pragma unroll
            for (int j = 0; j < 2; j++) {
                int sq = sbase + j * 16 + quad * 4;
                unsigned short t4[4];
                t4[0] = f2bf_rne(acc[2][i][j][0] + bvv);
                t4[1] = f2bf_rne(acc[2][i][j][1] + bvv);
                t4[2] = f2bf_rne(acc[2][i][j][2] + bvv);
                t4[3] = f2bf_rne(acc[2][i][j][3] + bvv);
                *(uint2*)(Vtb + (size_t)(b * DMODEL + oc) * S_LEN + sq) = *(uint2*)t4;
            }
        }
    }
}

// ---------------------------------------------------------------------------
// Kernel 2 (R16, kept): flash attention, q-tile 256 rows x 8 waves.
// R4 verified: dropped out of top-5 (<90 us).  LDS 48 KB -> 3 blocks/CU.
// ---------------------------------------------------------------------------
__global__ __launch_bounds__(512, 4) void flash_attn_mfma(
    const unsigned short* __restrict__ Qg,   // [B*S,1024] bf16, pre-scaled by CK
    const unsigned short* __restrict__ Kg,   // [B*S,1024] bf16
    const unsigned short* __restrict__ Vtg,  // [B,H,64,S] bf16
    unsigned short* __restrict__ ctxb)       // [B*S,1024] bf16
{
    __shared__ __align__(16) unsigned short Ks[16 * 512];  // 16 KB
    __shared__ __align__(16) unsigned short Vs[16 * 512];  // 16 KB
    __shared__ __align__(16) unsigned short Ps[16 * 512];  // 16 KB

    const int tid  = threadIdx.x;
    const int lane = tid & 63, w = tid >> 6;   // w 0..7
    const int quad = lane >> 4, l15 = lane & 15;

    // ---- XCD swizzle: 512 blocks; all 8 q-blocks of (b,h) on XCD bh%8 ----
    const int lin = blockIdx.x;            // 0..511
    const int xcd = lin & 7;
    const int s   = lin >> 3;              // 0..63
    const int bh  = xcd + 8 * (s >> 3);    // 0..63, bh%8 == xcd
    const int qblk = s & 7;                // 0..7
    const int b = bh >> 4, h = bh & 15;
    const int r0 = qblk * 256;

    bf16x8 qf[2][2];
    #pragma unroll
    for (int nt = 0; nt < 2; nt++)
        #pragma unroll
        for (int ds = 0; ds < 2; ds++)
            qf[nt][ds] = *(const bf16x8*)(Qg +
                (size_t)(b * S_LEN + r0 + w * 32 + nt * 16 + l15) * DMODEL +
                h * HD + ds * 32 + quad * 8);

    const int sw = w & 3;
    const unsigned short* gK = Kg +
        (size_t)(b * S_LEN + sw * 32 + l15) * DMODEL + h * HD + quad * 8;
    const unsigned short* gV = Vtg +
        ((size_t)(bh * HD + sw * 16 + l15)) * S_LEN + quad * 8;

    f32x4 O[2][4], lsum[2];
    #pragma unroll
    for (int rt = 0; rt < 2; rt++) {
        #pragma unroll
        for (int c = 0; c < 4; c++) lsum[rt][c] = 0.f;
        #pragma unroll
        for (int dt = 0; dt < 4; dt++)
            #pragma unroll
            for (int c = 0; c < 4; c++) O[rt][dt][c] = 0.f;
    }

    f32x4 zero4;
    #pragma unroll
    for (int c = 0; c < 4; c++) zero4[c] = 0.f;
    bf16x8 ones;
    #pragma unroll
    for (int c = 0; c < 8; c++) ones[c] = (short)0x3F80;   // bf16 1.0

    for (int st = 0; st < S_LEN / 128; st++) {
        __syncthreads();
        if (w < 4) {
            gld16(Ks + (w * 4 + 0) * 512, gK);
            gld16(Ks + (w * 4 + 1) * 512, gK + 32);
            gld16(Ks + (w * 4 + 2) * 512, gK + (size_t)16 * DMODEL);
            gld16(Ks + (w * 4 + 3) * 512, gK + (size_t)16 * DMODEL + 32);
            gK += (size_t)128 * DMODEL;
        } else {
            gld16(Vs + (sw * 4 + 0) * 512, gV);
            gld16(Vs + (sw * 4 + 1) * 512, gV + 32);
            gld16(Vs + (sw * 4 + 2) * 512, gV + 64);
            gld16(Vs + (sw * 4 + 3) * 512, gV + 96);
            gV += 128;
        }
        __syncthreads();

        #pragma unroll
        for (int r = 0; r < 4; r++) {
            f32x4 sc[2][2];
            {
                bf16x8 kf0 = *(const bf16x8*)&Ks[((r * 2 + 0) * 2 + 0) * 512 + lane * 8];
                bf16x8 kf1 = *(const bf16x8*)&Ks[((r * 2 + 1) * 2 + 0) * 512 + lane * 8];
                sc[0][0] = __builtin_amdgcn_mfma_f32_16x16x32_bf16(kf0, qf[0][0], zero4, 0, 0, 0);
                sc[0][1] = __builtin_amdgcn_mfma_f32_16x16x32_bf16(kf0, qf[1][0], zero4, 0, 0, 0);
                sc[1][0] = __builtin_amdgcn_mfma_f32_16x16x32_bf16(kf1, qf[0][0], zero4, 0, 0, 0);
                sc[1][1] = __builtin_amdgcn_mfma_f32_16x16x32_bf16(kf1, qf[1][0], zero4, 0, 0, 0);
                kf0 = *(const bf16x8*)&Ks[((r * 2 + 0) * 2 + 1) * 512 + lane * 8];
                kf1 = *(const bf16x8*)&Ks[((r * 2 + 1) * 2 + 1) * 512 + lane * 8];
                sc[0][0] = __builtin_amdgcn_mfma_f32_16x16x32_bf16(kf0, qf[0][1], sc[0][0], 0, 0, 0);
                sc[0][1] = __builtin_amdgcn_mfma_f32_16x16x32_bf16(kf0, qf[1][1], sc[0][1], 0, 0, 0);
                sc[1][0] = __builtin_amdgcn_mfma_f32_16x16x32_bf16(kf1, qf[0][1], sc[1][0], 0, 0, 0);
                sc[1][1] = __builtin_amdgcn_mfma_f32_16x16x32_bf16(kf1, qf[1][1], sc[1][1], 0, 0, 0);
            }

            #pragma unroll
            for (int nt = 0; nt < 2; nt++) {
                #pragma unroll
                for (int mt = 0; mt < 2; mt++) {
                    unsigned u[4];
                    #pragma unroll
                    for (int c = 0; c < 4; c++)
                        u[c] = __float_as_uint(__builtin_amdgcn_exp2f(sc[mt][nt][c]));
                    uint2 pk;
                    pk.x = __builtin_amdgcn_perm(u[1], u[0], 0x07060302u);
                    pk.y = __builtin_amdgcn_perm(u[3], u[2], 0x07060302u);
                    int off = (w * 2 + nt) * 512 + (mt * 2 + (quad >> 1)) * 128 +
                              l15 * 8 + (quad & 1) * 4;
                    *(uint2*)&Ps[off] = pk;
                }
            }

            bf16x8 pf0 = *(const bf16x8*)&Ps[(w * 2 + 0) * 512 + lane * 8];
            bf16x8 pf1 = *(const bf16x8*)&Ps[(w * 2 + 1) * 512 + lane * 8];
            lsum[0] = __builtin_amdgcn_mfma_f32_16x16x32_bf16(pf0, ones, lsum[0], 0, 0, 0);
            lsum[1] = __builtin_amdgcn_mfma_f32_16x16x32_bf16(pf1, ones, lsum[1], 0, 0, 0);
            #pragma unroll
            for (int dt = 0; dt < 4; dt++) {
                bf16x8 vf = *(const bf16x8*)&Vs[(dt * 4 + r) * 512 + lane * 8];
                O[0][dt] = __builtin_amdgcn_mfma_f32_16x16x32_bf16(pf0, vf, O[0][dt], 0, 0, 0);
                O[1][dt] = __builtin_amdgcn_mfma_f32_16x16x32_bf16(pf1, vf, O[1][dt], 0, 0, 0);
            }
        }
    }

    const size_t srow = (size_t)(b * S_LEN + r0 + w * 32);
    #pragma unroll
    for (int rt = 0; rt < 2; rt++) {
        #pragma unroll
        for (int reg = 0; reg < 4; reg++) {
            float li = 1.0f / lsum[rt][reg];
            size_t rowoff = (srow + rt * 16 + quad * 4 + reg) * DMODEL + h * HD + l15;
            #pragma unroll
            for (int dt = 0; dt < 4; dt++)
                ctxb[rowoff + dt * 16] = f2bf_rne(O[rt][dt][reg] * li);
        }
    }
}

// ---------------------------------------------------------------------------
// Kernel 3: output projection v4, 8-way K-split.  512 blocks x 512 thr.
// ---------------------------------------------------------------------------
__global__ __launch_bounds__(512) void out_proj_mfma(
    const unsigned short* __restrict__ ctxb,
    const unsigned short* __restrict__ WfT,
    const float* __restrict__ bfb,
    float* __restrict__ out)
{
    __shared__ float Red[8 * 1024];   // [wave][lane][j*4+reg], 32 KB

    const int tid = threadIdx.x;
    const int lane = tid & 63, w = tid >> 6;    // w 0..7
    const int quad = lane >> 4, l15 = lane & 15;
    const int m0 = blockIdx.x * 16;

    const unsigned short* pA = ctxb + (size_t)(m0 + l15) * DMODEL + w * 128 + quad * 8;
    const unsigned short* pB = WfT + (size_t)l15 * DMODEL + w * 128 + quad * 8;

    f32x4 acc[4];
    #pragma unroll
    for (int j = 0; j < 4; j++)
        #pragma unroll
        for (int c = 0; c < 4; c++) acc[j][c] = 0.f;

    #pragma unroll
    for (int k0 = 0; k0 < 128; k0 += 32) {
        bf16x8 af = *(const bf16x8*)(pA + k0);
        #pragma unroll
        for (int j = 0; j < 4; j++) {
            bf16x8 bfr = *(const bf16x8*)(pB + (size_t)j * 16 * DMODEL + k0);
            acc[j] = __builtin_amdgcn_mfma_f32_16x16x32_bf16(af, bfr, acc[j], 0, 0, 0);
        }
    }

    #pragma unroll
    for (int j = 0; j < 4; j++)
        #pragma unroll
        for (int reg = 0; reg < 4; reg++)
            Red[w * 1024 + lane * 16 + j * 4 + reg] = acc[j][reg];
    __syncthreads();

    const int row = tid >> 5;          // 0..15
    const int c0  = (tid & 31) * 2;    // 0..62
    float2 o;
    float* op = &o.x;
    #pragma unroll
    for (int cc = 0; cc < 2; cc++) {
        int col = c0 + cc;
        int idx = ((row >> 2) * 16 + (col & 15)) * 16 + (col >> 4) * 4 + (row & 3);
        float s = 0.f;
        #pragma unroll
        for (int wv = 0; wv < 8; wv++) s += Red[wv * 1024 + idx];
        op[cc] = s + bfb[col];
    }
    *(float2*)(out + (size_t)(m0 + row) * HD + c0) = o;
}

// ---------------------------------------------------------------------------
extern "C" void kernel_launch(void* const* d_in, const int* in_sizes, int n_in,
                              void* d_out, int out_size, void* d_ws, size_t ws_size,
                              hipStream_t stream)
{
    (void)in_sizes; (void)n_in; (void)out_size; (void)ws_size;
    const float* x  = (const float*)d_in[0];
    const float* Wq = (const float*)d_in[1];
    const float* bq = (const float*)d_in[2];
    const float* Wk = (const float*)d_in[3];
    const float* bk = (const float*)d_in[4];
    const float* Wv = (const float*)d_in[5];
    const float* bv = (const float*)d_in[6];
    const float* Wf = (const float*)d_in[7];
    const float* bf = (const float*)d_in[8];
    float* out = (float*)d_out;

    char* wsb = (char*)d_ws;
    unsigned short* xb   = (unsigned short*)wsb;            // 16 MB, dead after qkv
    unsigned short* ctxb = (unsigned short*)wsb;            // reuses xb region
    unsigned short* WT   = xb + (size_t)M_TOT * DMODEL;     // 3x2 MB + WfT
    unsigned short* WfT  = WT + (size_t)3 * DMODEL * DMODEL;
    unsigned short* Qb   = (unsigned short*)(wsb + (size_t)32 * 1024 * 1024);
    unsigned short* Kb   = Qb + (size_t)M_TOT * DMODEL;
    unsigned short* Vtb  = Kb + (size_t)M_TOT * DMODEL;

    cvt_fused<<<dim3(16, 16, 5), 256, 0, stream>>>(x, Wq, Wk, Wv, Wf, xb, WT);
    qkv_fused_mfma<<<dim3(512), 512, 0, stream>>>(xb, WT, bq, bk, bv, Qb, Kb, Vtb);
    flash_attn_mfma<<<dim3(512), 512, 0, stream>>>(Qb, Kb, Vtb, ctxb);
    out_proj_mfma<<<dim3(M_TOT / 16), 512, 0, stream>>>(ctxb, WfT, bf, out);
}

// Round 6
// 269.134 us; speedup vs baseline: 1.0296x; 1.0296x over previous
//
#include <hip/hip_runtime.h>
#include <math.h>

#define S_LEN 2048
#define NH 16
#define HD 64
#define DMODEL 1024
#define BATCH 4
#define M_TOT (BATCH * S_LEN)   // 8192

typedef __attribute__((ext_vector_type(8))) short bf16x8;
typedef __attribute__((ext_vector_type(4))) float f32x4;

#define CK 0.18033688f   // (1/sqrt(64)) * log2(e), folded into Q at projection

__device__ __forceinline__ unsigned short f2bf_rne(float f) {
    unsigned u = __float_as_uint(f);
    u += 0x7fffu + ((u >> 16) & 1u);
    return (unsigned short)(u >> 16);
}

__device__ __forceinline__ void gld16(unsigned short* lds, const unsigned short* g) {
    __builtin_amdgcn_global_load_lds(
        (const __attribute__((address_space(1))) void*)g,
        (__attribute__((address_space(3))) void*)lds, 16, 0, 0);
}

// ---------------------------------------------------------------------------
// cvt_fused: one dispatch for all input conversion.
// z=0..2: Wq/Wk/Wv [k][n] fp32 -> WT [n][k] bf16 (64x64 transpose tiles)
// z=3:    Wf (1024x64) -> WfT [64][1024]   (only blockIdx.x==0 active)
// z=4:    x fp32 -> bf16 (256 blocks x 32 float4/thread)
// ---------------------------------------------------------------------------
__global__ __launch_bounds__(256) void cvt_fused(
    const float* __restrict__ x,
    const float* __restrict__ Wq, const float* __restrict__ Wk,
    const float* __restrict__ Wv, const float* __restrict__ Wf,
    unsigned short* __restrict__ xb, unsigned short* __restrict__ WT)
{
    const int z = blockIdx.z;
    const int tid = threadIdx.x;

    if (z < 4) {
        if (z == 3 && blockIdx.x > 0) return;
        const float* W = (z == 0) ? Wq : (z == 1) ? Wk : (z == 2) ? Wv : Wf;
        const int ncol = (z == 3) ? 64 : DMODEL;
        unsigned short* out = WT + (size_t)z * DMODEL * DMODEL;

        __shared__ float Lt[64][65];
        const int r0 = blockIdx.y * 64;
        const int c0 = blockIdx.x * 64;

        #pragma unroll
        for (int p = 0; p < 4; p++) {
            int row = (tid >> 4) + p * 16;
            int c4 = (tid & 15) * 4;
            float4 v = *(const float4*)(W + (size_t)(r0 + row) * ncol + c0 + c4);
            Lt[row][c4 + 0] = v.x; Lt[row][c4 + 1] = v.y;
            Lt[row][c4 + 2] = v.z; Lt[row][c4 + 3] = v.w;
        }
        __syncthreads();
        #pragma unroll
        for (int p = 0; p < 4; p++) {
            int nr = (tid >> 4) + p * 16;
            int kc = (tid & 15) * 4;
            unsigned short t[4];
            #pragma unroll
            for (int j = 0; j < 4; j++) t[j] = f2bf_rne(Lt[kc + j][nr]);
            *(uint2*)(out + (size_t)(c0 + nr) * DMODEL + r0 + kc) = *(uint2*)t;
        }
    } else {
        const int gtid = (blockIdx.y * 16 + blockIdx.x) * 256 + tid;
        #pragma unroll
        for (int it = 0; it < 8; it++) {
            #pragma unroll
            for (int k = 0; k < 4; k++) {
                size_t i = ((size_t)((it * 4 + k) * 65536) + gtid) * 4;
                float4 v = *(const float4*)(x + i);
                unsigned short t[4];
                t[0] = f2bf_rne(v.x); t[1] = f2bf_rne(v.y);
                t[2] = f2bf_rne(v.z); t[3] = f2bf_rne(v.w);
                *(uint2*)(xb + i) = *(uint2*)t;
            }
        }
    }
}

// ---------------------------------------------------------------------------
// Kernel 1 (R18): FUSED QKV projection, BK=32 DOUBLE-BUFFER.
//   R0/R4/R5 triangulation: the binding resource is per-CU global_load_lds
//   completion rate, which scales with CONCURRENT STAGING STREAMS per CU
//   (R0: 4 blocks no-overlap = 10.7 TB/s agg; R4: 1 block + overlap = 5.1;
//   R5: 2 blocks no-overlap = 4.2).  This config gets BOTH: BK=32 halves
//   the stage buffer to 28 KB (x 16 + W 12), dbuf = 56 KB -> 2 resident
//   blocks/CU (512-block grid fully co-resident, 32 waves/CU) WITH the
//   R4-verified stage-before-compute overlap.  Staged bytes unchanged
//   (460 MB).  Staging roles: waves 0-3 stage W (3 gld16/step), waves 4-7
//   stage x (4 gld16/step).  Fragment reads / operand order (z==2 swapped
//   for V^T) / epilogues are the R4-verified code minus the sl loop.
// ---------------------------------------------------------------------------
__global__ __launch_bounds__(512) void qkv_fused_mfma(
    const unsigned short* __restrict__ xb,
    const unsigned short* __restrict__ WT,
    const float* __restrict__ bq, const float* __restrict__ bk,
    const float* __restrict__ bv,
    unsigned short* __restrict__ Qb, unsigned short* __restrict__ Kb,
    unsigned short* __restrict__ Vtb)
{
    // chunk = 512 shorts = 16 rows x 32 K.  W: 3z x 4 oc-groups = 12 chunks;
    // x: 16 row-groups = 16 chunks.  Per buffer 28 KB, dbuf 56 KB.
    __shared__ __align__(16) unsigned short Ws[2][12 * 512];   // 2 x 12 KB
    __shared__ __align__(16) unsigned short Bs[2][16 * 512];   // 2 x 16 KB

    const int lin = blockIdx.x;          // 0..511
    const int xcd = lin & 7;
    const int s   = lin >> 3;            // 0..63
    const int rb  = xcd * 4 + (s & 3);   // 0..31  (256-row tiles)
    const int ocb = s >> 2;              // 0..15  (64-oc tiles)

    const int tid = threadIdx.x;
    const int lane = tid & 63, w = tid >> 6;        // w 0..7
    const int quad = lane >> 4, l15 = lane & 15;
    const int sw = w & 3;                           // role-local wave index

    const int R0  = rb * 256;
    const int OC0 = ocb * 64;

    // W staging source (used by waves 0-3): oc-group sw, one chunk per z
    const unsigned short* gW0 = WT +
        (size_t)(OC0 + sw * 16 + l15) * DMODEL + quad * 8;
    const unsigned short* gW1 = gW0 + (size_t)DMODEL * DMODEL;
    const unsigned short* gW2 = gW1 + (size_t)DMODEL * DMODEL;
    // x staging sources (used by waves 4-7): row-groups sw*4 .. sw*4+3
    const unsigned short* gB0 = xb + (size_t)(R0 + (sw * 4 + 0) * 16 + l15) * DMODEL + quad * 8;
    const unsigned short* gB1 = gB0 + (size_t)16 * DMODEL;
    const unsigned short* gB2 = gB0 + (size_t)32 * DMODEL;
    const unsigned short* gB3 = gB0 + (size_t)48 * DMODEL;

    f32x4 acc[3][4][2];
    #pragma unroll
    for (int z = 0; z < 3; z++)
        #pragma unroll
        for (int i = 0; i < 4; i++)
            #pragma unroll
            for (int j = 0; j < 2; j++)
                #pragma unroll
                for (int c = 0; c < 4; c++) acc[z][i][j][c] = 0.f;

#define QKV_STAGE(BUF, K)  do {                                        \
        if (w < 4) {                                                   \
            gld16(Ws[BUF] + (0 * 4 + sw) * 512, gW0 + (K));            \
            gld16(Ws[BUF] + (1 * 4 + sw) * 512, gW1 + (K));            \
            gld16(Ws[BUF] + (2 * 4 + sw) * 512, gW2 + (K));            \
        } else {                                                       \
            gld16(Bs[BUF] + (sw * 4 + 0) * 512, gB0 + (K));            \
            gld16(Bs[BUF] + (sw * 4 + 1) * 512, gB1 + (K));            \
            gld16(Bs[BUF] + (sw * 4 + 2) * 512, gB2 + (K));            \
            gld16(Bs[BUF] + (sw * 4 + 3) * 512, gB3 + (K));            \
        }                                                              \
    } while (0)

    QKV_STAGE(0, 0);

    for (int t = 0; t < 32; ++t) {
        const int cur = t & 1;
        // barrier drains stage(t) (issued one compute-phase ago) and
        // guarantees all waves are done reading the buffer stage(t+1)
        // will overwrite.
        __syncthreads();
        if (t < 31) {
            if (cur == 0) QKV_STAGE(1, (t + 1) * 32);
            else          QKV_STAGE(0, (t + 1) * 32);
        }

        const unsigned short* Wb = Ws[cur];
        const unsigned short* Bb = Bs[cur];

        bf16x8 bfr[2];
        #pragma unroll
        for (int j = 0; j < 2; j++)
            bfr[j] = *(const bf16x8*)&Bb[(2 * w + j) * 512 + lane * 8];
        #pragma unroll
        for (int z = 0; z < 3; z++) {
            bf16x8 af[4];
            #pragma unroll
            for (int i = 0; i < 4; i++)
                af[i] = *(const bf16x8*)&Wb[(z * 4 + i) * 512 + lane * 8];
            if (z != 2) {
                #pragma unroll
                for (int i = 0; i < 4; i++)
                    #pragma unroll
                    for (int j = 0; j < 2; j++)
                        acc[z][i][j] = __builtin_amdgcn_mfma_f32_16x16x32_bf16(
                            af[i], bfr[j], acc[z][i][j], 0, 0, 0);
            } else {
                #pragma unroll
                for (int i = 0; i < 4; i++)
                    #pragma unroll
                    for (int j = 0; j < 2; j++)
                        acc[2][i][j] = __builtin_amdgcn_mfma_f32_16x16x32_bf16(
                            bfr[j], af[i], acc[2][i][j], 0, 0, 0);
            }
        }
    }
#undef QKV_STAGE

    #pragma unroll
    for (int z = 0; z < 2; z++) {
        unsigned short* out = (z == 0) ? Qb : Kb;
        const float* bias = (z == 0) ? bq : bk;
        const float qs = (z == 0) ? CK : 1.0f;
        #pragma unroll
        for (int i = 0; i < 4; i++) {
            int oc = OC0 + i * 16 + quad * 4;
            float4 bv4 = *(const float4*)&bias[oc];
            #pragma unroll
            for (int j = 0; j < 2; j++) {
                int row = R0 + w * 32 + j * 16 + l15;
                unsigned short t4[4];
                t4[0] = f2bf_rne((acc[z][i][j][0] + bv4.x) * qs);
                t4[1] = f2bf_rne((acc[z][i][j][1] + bv4.y) * qs);
                t4[2] = f2bf_rne((acc[z][i][j][2] + bv4.z) * qs);
                t4[3] = f2bf_rne((acc[z][i][j][3] + bv4.w) * qs);
                *(uint2*)(out + (size_t)row * DMODEL + oc) = *(uint2*)t4;
            }
        }
    }
    {
        const int b = R0 >> 11;
        const int sbase = (R0 & 2047) + w * 32;
        #pragma unroll
        for (int i = 0; i < 4; i++) {
            int oc = OC0 + i * 16 + l15;
            float bvv = bv[oc];
            #pragma unroll
            for (int j = 0; j < 2; j++) {
                int sq = sbase + j * 16 + quad * 4;
                unsigned short t4[4];
                t4[0] = f2bf_rne(acc[2][i][j][0] + bvv);
                t4[1] = f2bf_rne(acc[2][i][j][1] + bvv);
                t4[2] = f2bf_rne(acc[2][i][j][2] + bvv);
                t4[3] = f2bf_rne(acc[2][i][j][3] + bvv);
                *(uint2*)(Vtb + (size_t)(b * DMODEL + oc) * S_LEN + sq) = *(uint2*)t4;
            }
        }
    }
}

// ---------------------------------------------------------------------------
// Kernel 2 (R16, kept): flash attention, q-tile 256 rows x 8 waves.
// R4 verified: dropped out of top-5 (<90 us).  LDS 48 KB -> 3 blocks/CU.
// ---------------------------------------------------------------------------
__global__ __launch_bounds__(512, 4) void flash_attn_mfma(
    const unsigned short* __restrict__ Qg,   // [B*S,1024] bf16, pre-scaled by CK
    const unsigned short* __restrict__ Kg,   // [B*S,1024] bf16
    const unsigned short* __restrict__ Vtg,  // [B,H,64,S] bf16
    unsigned short* __restrict__ ctxb)       // [B*S,1024] bf16
{
    __shared__ __align__(16) unsigned short Ks[16 * 512];  // 16 KB
    __shared__ __align__(16) unsigned short Vs[16 * 512];  // 16 KB
    __shared__ __align__(16) unsigned short Ps[16 * 512];  // 16 KB

    const int tid  = threadIdx.x;
    const int lane = tid & 63, w = tid >> 6;   // w 0..7
    const int quad = lane >> 4, l15 = lane & 15;

    // ---- XCD swizzle: 512 blocks; all 8 q-blocks of (b,h) on XCD bh%8 ----
    const int lin = blockIdx.x;            // 0..511
    const int xcd = lin & 7;
    const int s   = lin >> 3;              // 0..63
    const int bh  = xcd + 8 * (s >> 3);    // 0..63, bh%8 == xcd
    const int qblk = s & 7;                // 0..7
    const int b = bh >> 4, h = bh & 15;
    const int r0 = qblk * 256;

    bf16x8 qf[2][2];
    #pragma unroll
    for (int nt = 0; nt < 2; nt++)
        #pragma unroll
        for (int ds = 0; ds < 2; ds++)
            qf[nt][ds] = *(const bf16x8*)(Qg +
                (size_t)(b * S_LEN + r0 + w * 32 + nt * 16 + l15) * DMODEL +
                h * HD + ds * 32 + quad * 8);

    const int sw = w & 3;
    const unsigned short* gK = Kg +
        (size_t)(b * S_LEN + sw * 32 + l15) * DMODEL + h * HD + quad * 8;
    const unsigned short* gV = Vtg +
        ((size_t)(bh * HD + sw * 16 + l15)) * S_LEN + quad * 8;

    f32x4 O[2][4], lsum[2];
    #pragma unroll
    for (int rt = 0; rt < 2; rt++) {
        #pragma unroll
        for (int c = 0; c < 4; c++) lsum[rt][c] = 0.f;
        #pragma unroll
        for (int dt = 0; dt < 4; dt++)
            #pragma unroll
            for (int c = 0; c < 4; c++) O[rt][dt][c] = 0.f;
    }

    f32x4 zero4;
    #pragma unroll
    for (int c = 0; c < 4; c++) zero4[c] = 0.f;
    bf16x8 ones;
    #pragma unroll
    for (int c = 0; c < 8; c++) ones[c] = (short)0x3F80;   // bf16 1.0

    for (int st = 0; st < S_LEN / 128; st++) {
        __syncthreads();
        if (w < 4) {
            gld16(Ks + (w * 4 + 0) * 512, gK);
            gld16(Ks + (w * 4 + 1) * 512, gK + 32);
            gld16(Ks + (w * 4 + 2) * 512, gK + (size_t)16 * DMODEL);
            gld16(Ks + (w * 4 + 3) * 512, gK + (size_t)16 * DMODEL + 32);
            gK += (size_t)128 * DMODEL;
        } else {
            gld16(Vs + (sw * 4 + 0) * 512, gV);
            gld16(Vs + (sw * 4 + 1) * 512, gV + 32);
            gld16(Vs + (sw * 4 + 2) * 512, gV + 64);
            gld16(Vs + (sw * 4 + 3) * 512, gV + 96);
            gV += 128;
        }
        __syncthreads();

        #pragma unroll
        for (int r = 0; r < 4; r++) {
            f32x4 sc[2][2];
            {
                bf16x8 kf0 = *(const bf16x8*)&Ks[((r * 2 + 0) * 2 + 0) * 512 + lane * 8];
                bf16x8 kf1 = *(const bf16x8*)&Ks[((r * 2 + 1) * 2 + 0) * 512 + lane * 8];
                sc[0][0] = __builtin_amdgcn_mfma_f32_16x16x32_bf16(kf0, qf[0][0], zero4, 0, 0, 0);
                sc[0][1] = __builtin_amdgcn_mfma_f32_16x16x32_bf16(kf0, qf[1][0], zero4, 0, 0, 0);
                sc[1][0] = __builtin_amdgcn_mfma_f32_16x16x32_bf16(kf1, qf[0][0], zero4, 0, 0, 0);
                sc[1][1] = __builtin_amdgcn_mfma_f32_16x16x32_bf16(kf1, qf[1][0], zero4, 0, 0, 0);
                kf0 = *(const bf16x8*)&Ks[((r * 2 + 0) * 2 + 1) * 512 + lane * 8];
                kf1 = *(const bf16x8*)&Ks[((r * 2 + 1) * 2 + 1) * 512 + lane * 8];
                sc[0][0] = __builtin_amdgcn_mfma_f32_16x16x32_bf16(kf0, qf[0][1], sc[0][0], 0, 0, 0);
                sc[0][1] = __builtin_amdgcn_mfma_f32_16x16x32_bf16(kf0, qf[1][1], sc[0][1], 0, 0, 0);
                sc[1][0] = __builtin_amdgcn_mfma_f32_16x16x32_bf16(kf1, qf[0][1], sc[1][0], 0, 0, 0);
                sc[1][1] = __builtin_amdgcn_mfma_f32_16x16x32_bf16(kf1, qf[1][1], sc[1][1], 0, 0, 0);
            }

            #pragma unroll
            for (int nt = 0; nt < 2; nt++) {
                #pragma unroll
                for (int mt = 0; mt < 2; mt++) {
                    unsigned u[4];
                    #pragma unroll
                    for (int c = 0; c < 4; c++)
                        u[c] = __float_as_uint(__builtin_amdgcn_exp2f(sc[mt][nt][c]));
                    uint2 pk;
                    pk.x = __builtin_amdgcn_perm(u[1], u[0], 0x07060302u);
                    pk.y = __builtin_amdgcn_perm(u[3], u[2], 0x07060302u);
                    int off = (w * 2 + nt) * 512 + (mt * 2 + (quad >> 1)) * 128 +
                              l15 * 8 + (quad & 1) * 4;
                    *(uint2*)&Ps[off] = pk;
                }
            }

            bf16x8 pf0 = *(const bf16x8*)&Ps[(w * 2 + 0) * 512 + lane * 8];
            bf16x8 pf1 = *(const bf16x8*)&Ps[(w * 2 + 1) * 512 + lane * 8];
            lsum[0] = __builtin_amdgcn_mfma_f32_16x16x32_bf16(pf0, ones, lsum[0], 0, 0, 0);
            lsum[1] = __builtin_amdgcn_mfma_f32_16x16x32_bf16(pf1, ones, lsum[1], 0, 0, 0);
            #pragma unroll
            for (int dt = 0; dt < 4; dt++) {
                bf16x8 vf = *(const bf16x8*)&Vs[(dt * 4 + r) * 512 + lane * 8];
                O[0][dt] = __builtin_amdgcn_mfma_f32_16x16x32_bf16(pf0, vf, O[0][dt], 0, 0, 0);
                O[1][dt] = __builtin_amdgcn_mfma_f32_16x16x32_bf16(pf1, vf, O[1][dt], 0, 0, 0);
            }
        }
    }

    const size_t srow = (size_t)(b * S_LEN + r0 + w * 32);
    #pragma unroll
    for (int rt = 0; rt < 2; rt++) {
        #pragma unroll
        for (int reg = 0; reg < 4; reg++) {
            float li = 1.0f / lsum[rt][reg];
            size_t rowoff = (srow + rt * 16 + quad * 4 + reg) * DMODEL + h * HD + l15;
            #pragma unroll
            for (int dt = 0; dt < 4; dt++)
                ctxb[rowoff + dt * 16] = f2bf_rne(O[rt][dt][reg] * li);
        }
    }
}

// ---------------------------------------------------------------------------
// Kernel 3: output projection v4, 8-way K-split.  512 blocks x 512 thr.
// ---------------------------------------------------------------------------
__global__ __launch_bounds__(512) void out_proj_mfma(
    const unsigned short* __restrict__ ctxb,
    const unsigned short* __restrict__ WfT,
    const float* __restrict__ bfb,
    float* __restrict__ out)
{
    __shared__ float Red[8 * 1024];   // [wave][lane][j*4+reg], 32 KB

    const int tid = threadIdx.x;
    const int lane = tid & 63, w = tid >> 6;    // w 0..7
    const int quad = lane >> 4, l15 = lane & 15;
    const int m0 = blockIdx.x * 16;

    const unsigned short* pA = ctxb + (size_t)(m0 + l15) * DMODEL + w * 128 + quad * 8;
    const unsigned short* pB = WfT + (size_t)l15 * DMODEL + w * 128 + quad * 8;

    f32x4 acc[4];
    #pragma unroll
    for (int j = 0; j < 4; j++)
        #pragma unroll
        for (int c = 0; c < 4; c++) acc[j][c] = 0.f;

    #pragma unroll
    for (int k0 = 0; k0 < 128; k0 += 32) {
        bf16x8 af = *(const bf16x8*)(pA + k0);
        #pragma unroll
        for (int j = 0; j < 4; j++) {
            bf16x8 bfr = *(const bf16x8*)(pB + (size_t)j * 16 * DMODEL + k0);
            acc[j] = __builtin_amdgcn_mfma_f32_16x16x32_bf16(af, bfr, acc[j], 0, 0, 0);
        }
    }

    #pragma unroll
    for (int j = 0; j < 4; j++)
        #pragma unroll
        for (int reg = 0; reg < 4; reg++)
            Red[w * 1024 + lane * 16 + j * 4 + reg] = acc[j][reg];
    __syncthreads();

    const int row = tid >> 5;          // 0..15
    const int c0  = (tid & 31) * 2;    // 0..62
    float2 o;
    float* op = &o.x;
    #pragma unroll
    for (int cc = 0; cc < 2; cc++) {
        int col = c0 + cc;
        int idx = ((row >> 2) * 16 + (col & 15)) * 16 + (col >> 4) * 4 + (row & 3);
        float s = 0.f;
        #pragma unroll
        for (int wv = 0; wv < 8; wv++) s += Red[wv * 1024 + idx];
        op[cc] = s + bfb[col];
    }
    *(float2*)(out + (size_t)(m0 + row) * HD + c0) = o;
}

// ---------------------------------------------------------------------------
extern "C" void kernel_launch(void* const* d_in, const int* in_sizes, int n_in,
                              void* d_out, int out_size, void* d_ws, size_t ws_size,
                              hipStream_t stream)
{
    (void)in_sizes; (void)n_in; (void)out_size; (void)ws_size;
    const float* x  = (const float*)d_in[0];
    const float* Wq = (const float*)d_in[1];
    const float* bq = (const float*)d_in[2];
    const float* Wk = (const float*)d_in[3];
    const float* bk = (const float*)d_in[4];
    const float* Wv = (const float*)d_in[5];
    const float* bv = (const float*)d_in[6];
    const float* Wf = (const float*)d_in[7];
    const float* bf = (const float*)d_in[8];
    float* out = (float*)d_out;

    char* wsb = (char*)d_ws;
    unsigned short* xb   = (unsigned short*)wsb;            // 16 MB, dead after qkv
    unsigned short* ctxb = (unsigned short*)wsb;            // reuses xb region
    unsigned short* WT   = xb + (size_t)M_TOT * DMODEL;     // 3x2 MB + WfT
    unsigned short* WfT  = WT + (size_t)3 * DMODEL * DMODEL;
    unsigned short* Qb   = (unsigned short*)(wsb + (size_t)32 * 1024 * 1024);
    unsigned short* Kb   = Qb + (size_t)M_TOT * DMODEL;
    unsigned short* Vtb  = Kb + (size_t)M_TOT * DMODEL;

    cvt_fused<<<dim3(16, 16, 5), 256, 0, stream>>>(x, Wq, Wk, Wv, Wf, xb, WT);
    qkv_fused_mfma<<<dim3(512), 512, 0, stream>>>(xb, WT, bq, bk, bv, Qb, Kb, Vtb);
    flash_attn_mfma<<<dim3(512), 512, 0, stream>>>(Qb, Kb, Vtb, ctxb);
    out_proj_mfma<<<dim3(M_TOT / 16), 512, 0, stream>>>(ctxb, WfT, bf, out);
}

// Round 7
// 256.907 us; speedup vs baseline: 1.0786x; 1.0476x over previous
//
#include <hip/hip_runtime.h>
#include <math.h>

#define S_LEN 2048
#define NH 16
#define HD 64
#define DMODEL 1024
#define BATCH 4
#define M_TOT (BATCH * S_LEN)   // 8192

typedef __attribute__((ext_vector_type(8))) short bf16x8;
typedef __attribute__((ext_vector_type(4))) float f32x4;

#define CK 0.18033688f   // (1/sqrt(64)) * log2(e), folded into Q at projection

__device__ __forceinline__ unsigned short f2bf_rne(float f) {
    unsigned u = __float_as_uint(f);
    u += 0x7fffu + ((u >> 16) & 1u);
    return (unsigned short)(u >> 16);
}

__device__ __forceinline__ void gld16(unsigned short* lds, const unsigned short* g) {
    __builtin_amdgcn_global_load_lds(
        (const __attribute__((address_space(1))) void*)g,
        (__attribute__((address_space(3))) void*)lds, 16, 0, 0);
}

// ---------------------------------------------------------------------------
// cvt_fused: one dispatch for all input conversion.
// z=0..2: Wq/Wk/Wv [k][n] fp32 -> WT [n][k] bf16 (64x64 transpose tiles)
// z=3:    Wf (1024x64) -> WfT [64][1024]   (only blockIdx.x==0 active)
// z=4:    x fp32 -> bf16 (256 blocks x 32 float4/thread)
// ---------------------------------------------------------------------------
__global__ __launch_bounds__(256) void cvt_fused(
    const float* __restrict__ x,
    const float* __restrict__ Wq, const float* __restrict__ Wk,
    const float* __restrict__ Wv, const float* __restrict__ Wf,
    unsigned short* __restrict__ xb, unsigned short* __restrict__ WT)
{
    const int z = blockIdx.z;
    const int tid = threadIdx.x;

    if (z < 4) {
        if (z == 3 && blockIdx.x > 0) return;
        const float* W = (z == 0) ? Wq : (z == 1) ? Wk : (z == 2) ? Wv : Wf;
        const int ncol = (z == 3) ? 64 : DMODEL;
        unsigned short* out = WT + (size_t)z * DMODEL * DMODEL;

        __shared__ float Lt[64][65];
        const int r0 = blockIdx.y * 64;
        const int c0 = blockIdx.x * 64;

        #pragma unroll
        for (int p = 0; p < 4; p++) {
            int row = (tid >> 4) + p * 16;
            int c4 = (tid & 15) * 4;
            float4 v = *(const float4*)(W + (size_t)(r0 + row) * ncol + c0 + c4);
            Lt[row][c4 + 0] = v.x; Lt[row][c4 + 1] = v.y;
            Lt[row][c4 + 2] = v.z; Lt[row][c4 + 3] = v.w;
        }
        __syncthreads();
        #pragma unroll
        for (int p = 0; p < 4; p++) {
            int nr = (tid >> 4) + p * 16;
            int kc = (tid & 15) * 4;
            unsigned short t[4];
            #pragma unroll
            for (int j = 0; j < 4; j++) t[j] = f2bf_rne(Lt[kc + j][nr]);
            *(uint2*)(out + (size_t)(c0 + nr) * DMODEL + r0 + kc) = *(uint2*)t;
        }
    } else {
        const int gtid = (blockIdx.y * 16 + blockIdx.x) * 256 + tid;
        #pragma unroll
        for (int it = 0; it < 8; it++) {
            #pragma unroll
            for (int k = 0; k < 4; k++) {
                size_t i = ((size_t)((it * 4 + k) * 65536) + gtid) * 4;
                float4 v = *(const float4*)(x + i);
                unsigned short t[4];
                t[0] = f2bf_rne(v.x); t[1] = f2bf_rne(v.y);
                t[2] = f2bf_rne(v.z); t[3] = f2bf_rne(v.w);
                *(uint2*)(xb + i) = *(uint2*)t;
            }
        }
    }
}

// ---------------------------------------------------------------------------
// Kernel 1 (R19): FUSED QKV, x DIRECT-TO-REGISTER, W in LDS.
//   R4/R6 model: T = steps x (0.7us fixed + coupled_bytes/~11GB/s/CU).
//   Key insight: x fragments are PER-WAVE-UNIQUE (chunk 2w+j only read by
//   wave w) -- x LDS staging had zero intra-block reuse (Common-mistake #7);
//   its z-reuse is in registers, cross-block reuse is L2's job either way.
//   So: x moves via direct global->reg bf16x8 loads, software-pipelined one
//   K-step ahead (xA/xB named dbuf, 2x manual unroll for static indexing).
//   Only W (shared by all 8 waves) stays in LDS: barrier-coupled staging
//   drops 56->24 KB/step.  W staging / fragment maps / MFMA order /
//   epilogues byte-identical to R4-verified code.  LDS 48 KB.
// ---------------------------------------------------------------------------
__global__ __launch_bounds__(512) void qkv_fused_mfma(
    const unsigned short* __restrict__ xb,
    const unsigned short* __restrict__ WT,
    const float* __restrict__ bq, const float* __restrict__ bk,
    const float* __restrict__ bv,
    unsigned short* __restrict__ Qb, unsigned short* __restrict__ Kb,
    unsigned short* __restrict__ Vtb)
{
    // W buffer: 3z x 4 oc-groups x 2 k-halves = 24 chunks of 512 shorts.
    __shared__ __align__(16) unsigned short Ws[2][24 * 512];   // 2 x 24 KB

    const int lin = blockIdx.x;          // 0..511
    const int xcd = lin & 7;
    const int s   = lin >> 3;            // 0..63
    const int rb  = xcd * 4 + (s & 3);   // 0..31  (256-row tiles)
    const int ocb = s >> 2;              // 0..15  (64-oc tiles)

    const int tid = threadIdx.x;
    const int lane = tid & 63, w = tid >> 6;        // w 0..7
    const int quad = lane >> 4, l15 = lane & 15;

    const int R0  = rb * 256;
    const int OC0 = ocb * 64;

    // W staging source (R4 layout): wave w supplies oc-group w>>1, k-half w&1
    const unsigned short* gW0 = WT +
        (size_t)(OC0 + (w >> 1) * 16 + l15) * DMODEL + (w & 1) * 32 + quad * 8;
    const unsigned short* gW1 = gW0 + (size_t)DMODEL * DMODEL;
    const unsigned short* gW2 = gW1 + (size_t)DMODEL * DMODEL;
    // x direct-load bases: wave w owns rows [R0+w*32, R0+w*32+32)
    const unsigned short* gx0 = xb +
        (size_t)(R0 + w * 32 + l15) * DMODEL + quad * 8;
    const unsigned short* gx1 = gx0 + (size_t)16 * DMODEL;

    f32x4 acc[3][4][2];
    #pragma unroll
    for (int z = 0; z < 3; z++)
        #pragma unroll
        for (int i = 0; i < 4; i++)
            #pragma unroll
            for (int j = 0; j < 2; j++)
                #pragma unroll
                for (int c = 0; c < 4; c++) acc[z][i][j][c] = 0.f;

#define QKV_STAGEW(BUF, K)  do {                                       \
        gld16(Ws[BUF] + (0 * 8 + w) * 512, gW0 + (K));                 \
        gld16(Ws[BUF] + (1 * 8 + w) * 512, gW1 + (K));                 \
        gld16(Ws[BUF] + (2 * 8 + w) * 512, gW2 + (K));                 \
    } while (0)

    // XF[j][sl]: j = 16-row group (j*16+l15), sl = 32-K half (sl*32+quad*8)
#define QKV_LOADX(XF, K)  do {                                         \
        XF[0][0] = *(const bf16x8*)(gx0 + (K));                        \
        XF[0][1] = *(const bf16x8*)(gx0 + (K) + 32);                   \
        XF[1][0] = *(const bf16x8*)(gx1 + (K));                        \
        XF[1][1] = *(const bf16x8*)(gx1 + (K) + 32);                   \
    } while (0)

#define QKV_COMPUTE(BUF, XF)  do {                                     \
        _Pragma("unroll")                                              \
        for (int sl = 0; sl < 2; sl++) {                               \
            _Pragma("unroll")                                          \
            for (int z = 0; z < 3; z++) {                              \
                bf16x8 af[4];                                          \
                _Pragma("unroll")                                      \
                for (int i = 0; i < 4; i++)                            \
                    af[i] = *(const bf16x8*)&Ws[BUF][(z * 8 + i * 2 + sl) * 512 + lane * 8]; \
                if (z != 2) {                                          \
                    _Pragma("unroll")                                  \
                    for (int i = 0; i < 4; i++)                        \
                        _Pragma("unroll")                              \
                        for (int j = 0; j < 2; j++)                    \
                            acc[z][i][j] = __builtin_amdgcn_mfma_f32_16x16x32_bf16( \
                                af[i], XF[j][sl], acc[z][i][j], 0, 0, 0); \
                } else {                                               \
                    _Pragma("unroll")                                  \
                    for (int i = 0; i < 4; i++)                        \
                        _Pragma("unroll")                              \
                        for (int j = 0; j < 2; j++)                    \
                            acc[2][i][j] = __builtin_amdgcn_mfma_f32_16x16x32_bf16( \
                                XF[j][sl], af[i], acc[2][i][j], 0, 0, 0); \
                }                                                      \
            }                                                          \
        }                                                              \
    } while (0)

    bf16x8 xA[2][2], xB[2][2];

    // prologue: W stage for t=0 into buf 0; x fragments for t=0
    QKV_STAGEW(0, 0);
    QKV_LOADX(xA, 0);

    // 16 K-steps, manually unrolled x2 for static xA/xB indexing
    #pragma unroll 1
    for (int tt = 0; tt < 16; tt += 2) {
        // ---- t = tt (even): compute from Ws[0], xA ----
        __syncthreads();                       // drains W stage(t) + x loads
        QKV_STAGEW(1, (tt + 1) * 64);          // tt+1 <= 15 always
        QKV_LOADX(xB, (tt + 1) * 64);
        QKV_COMPUTE(0, xA);

        // ---- t = tt+1 (odd): compute from Ws[1], xB ----
        __syncthreads();
        if (tt < 14) {
            QKV_STAGEW(0, (tt + 2) * 64);
            QKV_LOADX(xA, (tt + 2) * 64);
        }
        QKV_COMPUTE(1, xB);
    }
#undef QKV_STAGEW
#undef QKV_LOADX
#undef QKV_COMPUTE

    #pragma unroll
    for (int z = 0; z < 2; z++) {
        unsigned short* out = (z == 0) ? Qb : Kb;
        const float* bias = (z == 0) ? bq : bk;
        const float qs = (z == 0) ? CK : 1.0f;
        #pragma unroll
        for (int i = 0; i < 4; i++) {
            int oc = OC0 + i * 16 + quad * 4;
            float4 bv4 = *(const float4*)&bias[oc];
            #pragma unroll
            for (int j = 0; j < 2; j++) {
                int row = R0 + w * 32 + j * 16 + l15;
                unsigned short t4[4];
                t4[0] = f2bf_rne((acc[z][i][j][0] + bv4.x) * qs);
                t4[1] = f2bf_rne((acc[z][i][j][1] + bv4.y) * qs);
                t4[2] = f2bf_rne((acc[z][i][j][2] + bv4.z) * qs);
                t4[3] = f2bf_rne((acc[z][i][j][3] + bv4.w) * qs);
                *(uint2*)(out + (size_t)row * DMODEL + oc) = *(uint2*)t4;
            }
        }
    }
    {
        const int b = R0 >> 11;
        const int sbase = (R0 & 2047) + w * 32;
        #pragma unroll
        for (int i = 0; i < 4; i++) {
            int oc = OC0 + i * 16 + l15;
            float bvv = bv[oc];
            #pragma unroll
            for (int j = 0; j < 2; j++) {
                int sq = sbase + j * 16 + quad * 4;
                unsigned short t4[4];
                t4[0] = f2bf_rne(acc[2][i][j][0] + bvv);
                t4[1] = f2bf_rne(acc[2][i][j][1] + bvv);
                t4[2] = f2bf_rne(acc[2][i][j][2] + bvv);
                t4[3] = f2bf_rne(acc[2][i][j][3] + bvv);
                *(uint2*)(Vtb + (size_t)(b * DMODEL + oc) * S_LEN + sq) = *(uint2*)t4;
            }
        }
    }
}

// ---------------------------------------------------------------------------
// Kernel 2 (R16, kept): flash attention, q-tile 256 rows x 8 waves.
// R4 verified: dropped out of top-5 (<90 us).  K/V/P LDS is genuinely
// wave-shared (unlike qkv's x), so staging stays.
// ---------------------------------------------------------------------------
__global__ __launch_bounds__(512, 4) void flash_attn_mfma(
    const unsigned short* __restrict__ Qg,   // [B*S,1024] bf16, pre-scaled by CK
    const unsigned short* __restrict__ Kg,   // [B*S,1024] bf16
    const unsigned short* __restrict__ Vtg,  // [B,H,64,S] bf16
    unsigned short* __restrict__ ctxb)       // [B*S,1024] bf16
{
    __shared__ __align__(16) unsigned short Ks[16 * 512];  // 16 KB
    __shared__ __align__(16) unsigned short Vs[16 * 512];  // 16 KB
    __shared__ __align__(16) unsigned short Ps[16 * 512];  // 16 KB

    const int tid  = threadIdx.x;
    const int lane = tid & 63, w = tid >> 6;   // w 0..7
    const int quad = lane >> 4, l15 = lane & 15;

    // ---- XCD swizzle: 512 blocks; all 8 q-blocks of (b,h) on XCD bh%8 ----
    const int lin = blockIdx.x;            // 0..511
    const int xcd = lin & 7;
    const int s   = lin >> 3;              // 0..63
    const int bh  = xcd + 8 * (s >> 3);    // 0..63, bh%8 == xcd
    const int qblk = s & 7;                // 0..7
    const int b = bh >> 4, h = bh & 15;
    const int r0 = qblk * 256;

    bf16x8 qf[2][2];
    #pragma unroll
    for (int nt = 0; nt < 2; nt++)
        #pragma unroll
        for (int ds = 0; ds < 2; ds++)
            qf[nt][ds] = *(const bf16x8*)(Qg +
                (size_t)(b * S_LEN + r0 + w * 32 + nt * 16 + l15) * DMODEL +
                h * HD + ds * 32 + quad * 8);

    const int sw = w & 3;
    const unsigned short* gK = Kg +
        (size_t)(b * S_LEN + sw * 32 + l15) * DMODEL + h * HD + quad * 8;
    const unsigned short* gV = Vtg +
        ((size_t)(bh * HD + sw * 16 + l15)) * S_LEN + quad * 8;

    f32x4 O[2][4], lsum[2];
    #pragma unroll
    for (int rt = 0; rt < 2; rt++) {
        #pragma unroll
        for (int c = 0; c < 4; c++) lsum[rt][c] = 0.f;
        #pragma unroll
        for (int dt = 0; dt < 4; dt++)
            #pragma unroll
            for (int c = 0; c < 4; c++) O[rt][dt][c] = 0.f;
    }

    f32x4 zero4;
    #pragma unroll
    for (int c = 0; c < 4; c++) zero4[c] = 0.f;
    bf16x8 ones;
    #pragma unroll
    for (int c = 0; c < 8; c++) ones[c] = (short)0x3F80;   // bf16 1.0

    for (int st = 0; st < S_LEN / 128; st++) {
        __syncthreads();
        if (w < 4) {
            gld16(Ks + (w * 4 + 0) * 512, gK);
            gld16(Ks + (w * 4 + 1) * 512, gK + 32);
            gld16(Ks + (w * 4 + 2) * 512, gK + (size_t)16 * DMODEL);
            gld16(Ks + (w * 4 + 3) * 512, gK + (size_t)16 * DMODEL + 32);
            gK += (size_t)128 * DMODEL;
        } else {
            gld16(Vs + (sw * 4 + 0) * 512, gV);
            gld16(Vs + (sw * 4 + 1) * 512, gV + 32);
            gld16(Vs + (sw * 4 + 2) * 512, gV + 64);
            gld16(Vs + (sw * 4 + 3) * 512, gV + 96);
            gV += 128;
        }
        __syncthreads();

        #pragma unroll
        for (int r = 0; r < 4; r++) {
            f32x4 sc[2][2];
            {
                bf16x8 kf0 = *(const bf16x8*)&Ks[((r * 2 + 0) * 2 + 0) * 512 + lane * 8];
                bf16x8 kf1 = *(const bf16x8*)&Ks[((r * 2 + 1) * 2 + 0) * 512 + lane * 8];
                sc[0][0] = __builtin_amdgcn_mfma_f32_16x16x32_bf16(kf0, qf[0][0], zero4, 0, 0, 0);
                sc[0][1] = __builtin_amdgcn_mfma_f32_16x16x32_bf16(kf0, qf[1][0], zero4, 0, 0, 0);
                sc[1][0] = __builtin_amdgcn_mfma_f32_16x16x32_bf16(kf1, qf[0][0], zero4, 0, 0, 0);
                sc[1][1] = __builtin_amdgcn_mfma_f32_16x16x32_bf16(kf1, qf[1][0], zero4, 0, 0, 0);
                kf0 = *(const bf16x8*)&Ks[((r * 2 + 0) * 2 + 1) * 512 + lane * 8];
                kf1 = *(const bf16x8*)&Ks[((r * 2 + 1) * 2 + 1) * 512 + lane * 8];
                sc[0][0] = __builtin_amdgcn_mfma_f32_16x16x32_bf16(kf0, qf[0][1], sc[0][0], 0, 0, 0);
                sc[0][1] = __builtin_amdgcn_mfma_f32_16x16x32_bf16(kf0, qf[1][1], sc[0][1], 0, 0, 0);
                sc[1][0] = __builtin_amdgcn_mfma_f32_16x16x32_bf16(kf1, qf[0][1], sc[1][0], 0, 0, 0);
                sc[1][1] = __builtin_amdgcn_mfma_f32_16x16x32_bf16(kf1, qf[1][1], sc[1][1], 0, 0, 0);
            }

            #pragma unroll
            for (int nt = 0; nt < 2; nt++) {
                #pragma unroll
                for (int mt = 0; mt < 2; mt++) {
                    unsigned u[4];
                    #pragma unroll
                    for (int c = 0; c < 4; c++)
                        u[c] = __float_as_uint(__builtin_amdgcn_exp2f(sc[mt][nt][c]));
                    uint2 pk;
                    pk.x = __builtin_amdgcn_perm(u[1], u[0], 0x07060302u);
                    pk.y = __builtin_amdgcn_perm(u[3], u[2], 0x07060302u);
                    int off = (w * 2 + nt) * 512 + (mt * 2 + (quad >> 1)) * 128 +
                              l15 * 8 + (quad & 1) * 4;
                    *(uint2*)&Ps[off] = pk;
                }
            }

            bf16x8 pf0 = *(const bf16x8*)&Ps[(w * 2 + 0) * 512 + lane * 8];
            bf16x8 pf1 = *(const bf16x8*)&Ps[(w * 2 + 1) * 512 + lane * 8];
            lsum[0] = __builtin_amdgcn_mfma_f32_16x16x32_bf16(pf0, ones, lsum[0], 0, 0, 0);
            lsum[1] = __builtin_amdgcn_mfma_f32_16x16x32_bf16(pf1, ones, lsum[1], 0, 0, 0);
            #pragma unroll
            for (int dt = 0; dt < 4; dt++) {
                bf16x8 vf = *(const bf16x8*)&Vs[(dt * 4 + r) * 512 + lane * 8];
                O[0][dt] = __builtin_amdgcn_mfma_f32_16x16x32_bf16(pf0, vf, O[0][dt], 0, 0, 0);
                O[1][dt] = __builtin_amdgcn_mfma_f32_16x16x32_bf16(pf1, vf, O[1][dt], 0, 0, 0);
            }
        }
    }

    const size_t srow = (size_t)(b * S_LEN + r0 + w * 32);
    #pragma unroll
    for (int rt = 0; rt < 2; rt++) {
        #pragma unroll
        for (int reg = 0; reg < 4; reg++) {
            float li = 1.0f / lsum[rt][reg];
            size_t rowoff = (srow + rt * 16 + quad * 4 + reg) * DMODEL + h * HD + l15;
            #pragma unroll
            for (int dt = 0; dt < 4; dt++)
                ctxb[rowoff + dt * 16] = f2bf_rne(O[rt][dt][reg] * li);
        }
    }
}

// ---------------------------------------------------------------------------
// Kernel 3: output projection v4, 8-way K-split.  512 blocks x 512 thr.
// ---------------------------------------------------------------------------
__global__ __launch_bounds__(512) void out_proj_mfma(
    const unsigned short* __restrict__ ctxb,
    const unsigned short* __restrict__ WfT,
    const float* __restrict__ bfb,
    float* __restrict__ out)
{
    __shared__ float Red[8 * 1024];   // [wave][lane][j*4+reg], 32 KB

    const int tid = threadIdx.x;
    const int lane = tid & 63, w = tid >> 6;    // w 0..7
    const int quad = lane >> 4, l15 = lane & 15;
    const int m0 = blockIdx.x * 16;

    const unsigned short* pA = ctxb + (size_t)(m0 + l15) * DMODEL + w * 128 + quad * 8;
    const unsigned short* pB = WfT + (size_t)l15 * DMODEL + w * 128 + quad * 8;

    f32x4 acc[4];
    #pragma unroll
    for (int j = 0; j < 4; j++)
        #pragma unroll
        for (int c = 0; c < 4; c++) acc[j][c] = 0.f;

    #pragma unroll
    for (int k0 = 0; k0 < 128; k0 += 32) {
        bf16x8 af = *(const bf16x8*)(pA + k0);
        #pragma unroll
        for (int j = 0; j < 4; j++) {
            bf16x8 bfr = *(const bf16x8*)(pB + (size_t)j * 16 * DMODEL + k0);
            acc[j] = __builtin_amdgcn_mfma_f32_16x16x32_bf16(af, bfr, acc[j], 0, 0, 0);
        }
    }

    #pragma unroll
    for (int j = 0; j < 4; j++)
        #pragma unroll
        for (int reg = 0; reg < 4; reg++)
            Red[w * 1024 + lane * 16 + j * 4 + reg] = acc[j][reg];
    __syncthreads();

    const int row = tid >> 5;          // 0..15
    const int c0  = (tid & 31) * 2;    // 0..62
    float2 o;
    float* op = &o.x;
    #pragma unroll
    for (int cc = 0; cc < 2; cc++) {
        int col = c0 + cc;
        int idx = ((row >> 2) * 16 + (col & 15)) * 16 + (col >> 4) * 4 + (row & 3);
        float s = 0.f;
        #pragma unroll
        for (int wv = 0; wv < 8; wv++) s += Red[wv * 1024 + idx];
        op[cc] = s + bfb[col];
    }
    *(float2*)(out + (size_t)(m0 + row) * HD + c0) = o;
}

// ---------------------------------------------------------------------------
extern "C" void kernel_launch(void* const* d_in, const int* in_sizes, int n_in,
                              void* d_out, int out_size, void* d_ws, size_t ws_size,
                              hipStream_t stream)
{
    (void)in_sizes; (void)n_in; (void)out_size; (void)ws_size;
    const float* x  = (const float*)d_in[0];
    const float* Wq = (const float*)d_in[1];
    const float* bq = (const float*)d_in[2];
    const float* Wk = (const float*)d_in[3];
    const float* bk = (const float*)d_in[4];
    const float* Wv = (const float*)d_in[5];
    const float* bv = (const float*)d_in[6];
    const float* Wf = (const float*)d_in[7];
    const float* bf = (const float*)d_in[8];
    float* out = (float*)d_out;

    char* wsb = (char*)d_ws;
    unsigned short* xb   = (unsigned short*)wsb;            // 16 MB, dead after qkv
    unsigned short* ctxb = (unsigned short*)wsb;            // reuses xb region
    unsigned short* WT   = xb + (size_t)M_TOT * DMODEL;     // 3x2 MB + WfT
    unsigned short* WfT  = WT + (size_t)3 * DMODEL * DMODEL;
    unsigned short* Qb   = (unsigned short*)(wsb + (size_t)32 * 1024 * 1024);
    unsigned short* Kb   = Qb + (size_t)M_TOT * DMODEL;
    unsigned short* Vtb  = Kb + (size_t)M_TOT * DMODEL;

    cvt_fused<<<dim3(16, 16, 5), 256, 0, stream>>>(x, Wq, Wk, Wv, Wf, xb, WT);
    qkv_fused_mfma<<<dim3(512), 512, 0, stream>>>(xb, WT, bq, bk, bv, Qb, Kb, Vtb);
    flash_attn_mfma<<<dim3(512), 512, 0, stream>>>(Qb, Kb, Vtb, ctxb);
    out_proj_mfma<<<dim3(M_TOT / 16), 512, 0, stream>>>(ctxb, WfT, bf, out);
}

// Round 8
// 253.812 us; speedup vs baseline: 1.0917x; 1.0122x over previous
//
#include <hip/hip_runtime.h>
#include <math.h>

#define S_LEN 2048
#define NH 16
#define HD 64
#define DMODEL 1024
#define BATCH 4
#define M_TOT (BATCH * S_LEN)   // 8192

typedef __attribute__((ext_vector_type(8))) short bf16x8;
typedef __attribute__((ext_vector_type(4))) float f32x4;

#define CK 0.18033688f   // (1/sqrt(64)) * log2(e), folded into Q at projection

__device__ __forceinline__ unsigned short f2bf_rne(float f) {
    unsigned u = __float_as_uint(f);
    u += 0x7fffu + ((u >> 16) & 1u);
    return (unsigned short)(u >> 16);
}

__device__ __forceinline__ void gld16(unsigned short* lds, const unsigned short* g) {
    __builtin_amdgcn_global_load_lds(
        (const __attribute__((address_space(1))) void*)g,
        (__attribute__((address_space(3))) void*)lds, 16, 0, 0);
}

// ---------------------------------------------------------------------------
// cvt_fused: one dispatch for all input conversion.
// z=0..2: Wq/Wk/Wv [k][n] fp32 -> WT [n][k] bf16 (64x64 transpose tiles)
// z=3:    Wf (1024x64) -> WfT [64][1024]   (only blockIdx.x==0 active)
// z=4:    x fp32 -> bf16 (256 blocks x 32 float4/thread)
// ---------------------------------------------------------------------------
__global__ __launch_bounds__(256) void cvt_fused(
    const float* __restrict__ x,
    const float* __restrict__ Wq, const float* __restrict__ Wk,
    const float* __restrict__ Wv, const float* __restrict__ Wf,
    unsigned short* __restrict__ xb, unsigned short* __restrict__ WT)
{
    const int z = blockIdx.z;
    const int tid = threadIdx.x;

    if (z < 4) {
        if (z == 3 && blockIdx.x > 0) return;
        const float* W = (z == 0) ? Wq : (z == 1) ? Wk : (z == 2) ? Wv : Wf;
        const int ncol = (z == 3) ? 64 : DMODEL;
        unsigned short* out = WT + (size_t)z * DMODEL * DMODEL;

        __shared__ float Lt[64][65];
        const int r0 = blockIdx.y * 64;
        const int c0 = blockIdx.x * 64;

        #pragma unroll
        for (int p = 0; p < 4; p++) {
            int row = (tid >> 4) + p * 16;
            int c4 = (tid & 15) * 4;
            float4 v = *(const float4*)(W + (size_t)(r0 + row) * ncol + c0 + c4);
            Lt[row][c4 + 0] = v.x; Lt[row][c4 + 1] = v.y;
            Lt[row][c4 + 2] = v.z; Lt[row][c4 + 3] = v.w;
        }
        __syncthreads();
        #pragma unroll
        for (int p = 0; p < 4; p++) {
            int nr = (tid >> 4) + p * 16;
            int kc = (tid & 15) * 4;
            unsigned short t[4];
            #pragma unroll
            for (int j = 0; j < 4; j++) t[j] = f2bf_rne(Lt[kc + j][nr]);
            *(uint2*)(out + (size_t)(c0 + nr) * DMODEL + r0 + kc) = *(uint2*)t;
        }
    } else {
        const int gtid = (blockIdx.y * 16 + blockIdx.x) * 256 + tid;
        #pragma unroll
        for (int it = 0; it < 8; it++) {
            #pragma unroll
            for (int k = 0; k < 4; k++) {
                size_t i = ((size_t)((it * 4 + k) * 65536) + gtid) * 4;
                float4 v = *(const float4*)(x + i);
                unsigned short t[4];
                t[0] = f2bf_rne(v.x); t[1] = f2bf_rne(v.y);
                t[2] = f2bf_rne(v.z); t[3] = f2bf_rne(v.w);
                *(uint2*)(xb + i) = *(uint2*)t;
            }
        }
    }
}

// ---------------------------------------------------------------------------
// Kernel 1 (R20): FUSED QKV, x in regs (2-deep), W in LDS 3-BUFFER RING,
// COUNTED vmcnt + RAW s_barrier (T4 applied to the working R7 geometry).
//   R7 post-mortem: every variant stalls because __syncthreads drains
//   vmcnt(0) for data issued ONE phase earlier (1-deep pipeline).  m218:
//   counted-vs-drain0 is the +38-73% lever.  Protocol per step t:
//     s_waitcnt vmcnt(3)   // only W(t+1)'s 3 gld16 stay in flight;
//                          // W(t) in LDS + x(t) in regs are complete
//     s_barrier            // no drain; all waves' W(t) stages done
//     issue x(t+1) [4 loads]  THEN  W(t+2) [3 gld16]  (newest-3 = W)
//     compute(t)
//   Tail (t=15) waits vmcnt(0).  Buffer safety: stage(t+2) overwrites the
//   buffer last read at compute(t-1); all waves finished that before this
//   barrier.  Every ds_read is consumed by an MFMA before barrier arrival,
//   so no LDS reads are in flight across it.  LDS 72 KB -> 2 blocks/CU.
//   Fragment maps / MFMA order / epilogues byte-identical to R7 (passing).
// ---------------------------------------------------------------------------
__global__ __launch_bounds__(512) void qkv_fused_mfma(
    const unsigned short* __restrict__ xb,
    const unsigned short* __restrict__ WT,
    const float* __restrict__ bq, const float* __restrict__ bk,
    const float* __restrict__ bv,
    unsigned short* __restrict__ Qb, unsigned short* __restrict__ Kb,
    unsigned short* __restrict__ Vtb)
{
    // W ring: 3 buffers x 24 chunks (3z x 4 oc-groups x 2 k-halves) x 512.
    __shared__ __align__(16) unsigned short Ws[3][24 * 512];   // 72 KB

    const int lin = blockIdx.x;          // 0..511
    const int xcd = lin & 7;
    const int s   = lin >> 3;            // 0..63
    const int rb  = xcd * 4 + (s & 3);   // 0..31  (256-row tiles)
    const int ocb = s >> 2;              // 0..15  (64-oc tiles)

    const int tid = threadIdx.x;
    const int lane = tid & 63, w = tid >> 6;        // w 0..7
    const int quad = lane >> 4, l15 = lane & 15;

    const int R0  = rb * 256;
    const int OC0 = ocb * 64;

    // W staging source: wave w supplies oc-group w>>1, k-half w&1
    const unsigned short* gW0 = WT +
        (size_t)(OC0 + (w >> 1) * 16 + l15) * DMODEL + (w & 1) * 32 + quad * 8;
    const unsigned short* gW1 = gW0 + (size_t)DMODEL * DMODEL;
    const unsigned short* gW2 = gW1 + (size_t)DMODEL * DMODEL;
    // x direct-load bases: wave w owns rows [R0+w*32, R0+w*32+32)
    const unsigned short* gx0 = xb +
        (size_t)(R0 + w * 32 + l15) * DMODEL + quad * 8;
    const unsigned short* gx1 = gx0 + (size_t)16 * DMODEL;

    f32x4 acc[3][4][2];
    #pragma unroll
    for (int z = 0; z < 3; z++)
        #pragma unroll
        for (int i = 0; i < 4; i++)
            #pragma unroll
            for (int j = 0; j < 2; j++)
                #pragma unroll
                for (int c = 0; c < 4; c++) acc[z][i][j][c] = 0.f;

#define QKV_STAGEW(BUF, K)  do {                                       \
        gld16(Ws[BUF] + (0 * 8 + w) * 512, gW0 + (K));                 \
        gld16(Ws[BUF] + (1 * 8 + w) * 512, gW1 + (K));                 \
        gld16(Ws[BUF] + (2 * 8 + w) * 512, gW2 + (K));                 \
    } while (0)

    // XF[j][sl]: j = 16-row group (j*16+l15), sl = 32-K half (sl*32+quad*8)
#define QKV_LOADX(XF, K)  do {                                         \
        XF[0][0] = *(const bf16x8*)(gx0 + (K));                        \
        XF[0][1] = *(const bf16x8*)(gx0 + (K) + 32);                   \
        XF[1][0] = *(const bf16x8*)(gx1 + (K));                        \
        XF[1][1] = *(const bf16x8*)(gx1 + (K) + 32);                   \
    } while (0)

#define QKV_COMPUTE(BUF, XF)  do {                                     \
        _Pragma("unroll")                                              \
        for (int sl = 0; sl < 2; sl++) {                               \
            _Pragma("unroll")                                          \
            for (int z = 0; z < 3; z++) {                              \
                bf16x8 af[4];                                          \
                _Pragma("unroll")                                      \
                for (int i = 0; i < 4; i++)                            \
                    af[i] = *(const bf16x8*)&Ws[BUF][(z * 8 + i * 2 + sl) * 512 + lane * 8]; \
                if (z != 2) {                                          \
                    _Pragma("unroll")                                  \
                    for (int i = 0; i < 4; i++)                        \
                        _Pragma("unroll")                              \
                        for (int j = 0; j < 2; j++)                    \
                            acc[z][i][j] = __builtin_amdgcn_mfma_f32_16x16x32_bf16( \
                                af[i], XF[j][sl], acc[z][i][j], 0, 0, 0); \
                } else {                                               \
                    _Pragma("unroll")                                  \
                    for (int i = 0; i < 4; i++)                        \
                        _Pragma("unroll")                              \
                        for (int j = 0; j < 2; j++)                    \
                            acc[2][i][j] = __builtin_amdgcn_mfma_f32_16x16x32_bf16( \
                                XF[j][sl], af[i], acc[2][i][j], 0, 0, 0); \
                }                                                      \
            }                                                          \
        }                                                              \
    } while (0)

    bf16x8 xA[2][2], xB[2][2];

    // prologue: W(0)->buf0, x(0), W(1)->buf1  (newest-3 = W(1))
    QKV_STAGEW(0, 0);
    QKV_LOADX(xA, 0);
    QKV_STAGEW(1, 64);

    int b0 = 0;   // buffer holding step tt's W
    #pragma unroll 1
    for (int tt = 0; tt < 16; tt += 2) {
        const int b1 = (b0 + 1 == 3) ? 0 : b0 + 1;
        const int b2 = (b1 + 1 == 3) ? 0 : b1 + 1;

        // ---- even step t = tt : W in Ws[b0], x in xA ----
        asm volatile("s_waitcnt vmcnt(3)" ::: "memory");
        __builtin_amdgcn_s_barrier();
        if (tt < 15) QKV_LOADX(xB, (tt + 1) * 64);      // x(t+1) first
        if (tt < 14) QKV_STAGEW(b2, (tt + 2) * 64);     // then W(t+2): newest-3
        QKV_COMPUTE(b0, xA);

        // ---- odd step t = tt+1 : W in Ws[b1], x in xB ----
        if (tt < 14) asm volatile("s_waitcnt vmcnt(3)" ::: "memory");
        else         asm volatile("s_waitcnt vmcnt(0)" ::: "memory");
        __builtin_amdgcn_s_barrier();
        if (tt < 14) QKV_LOADX(xA, (tt + 2) * 64);      // x(t+1)
        if (tt < 13) QKV_STAGEW(b0, (tt + 3) * 64);     // W(t+2) -> b0
        QKV_COMPUTE(b1, xB);

        b0 = b2;
    }
#undef QKV_STAGEW
#undef QKV_LOADX
#undef QKV_COMPUTE

    #pragma unroll
    for (int z = 0; z < 2; z++) {
        unsigned short* out = (z == 0) ? Qb : Kb;
        const float* bias = (z == 0) ? bq : bk;
        const float qs = (z == 0) ? CK : 1.0f;
        #pragma unroll
        for (int i = 0; i < 4; i++) {
            int oc = OC0 + i * 16 + quad * 4;
            float4 bv4 = *(const float4*)&bias[oc];
            #pragma unroll
            for (int j = 0; j < 2; j++) {
                int row = R0 + w * 32 + j * 16 + l15;
                unsigned short t4[4];
                t4[0] = f2bf_rne((acc[z][i][j][0] + bv4.x) * qs);
                t4[1] = f2bf_rne((acc[z][i][j][1] + bv4.y) * qs);
                t4[2] = f2bf_rne((acc[z][i][j][2] + bv4.z) * qs);
                t4[3] = f2bf_rne((acc[z][i][j][3] + bv4.w) * qs);
                *(uint2*)(out + (size_t)row * DMODEL + oc) = *(uint2*)t4;
            }
        }
    }
    {
        const int b = R0 >> 11;
        const int sbase = (R0 & 2047) + w * 32;
        #pragma unroll
        for (int i = 0; i < 4; i++) {
            int oc = OC0 + i * 16 + l15;
            float bvv = bv[oc];
            #pragma unroll
            for (int j = 0; j < 2; j++) {
                int sq = sbase + j * 16 + quad * 4;
                unsigned short t4[4];
                t4[0] = f2bf_rne(acc[2][i][j][0] + bvv);
                t4[1] = f2bf_rne(acc[2][i][j][1] + bvv);
                t4[2] = f2bf_rne(acc[2][i][j][2] + bvv);
                t4[3] = f2bf_rne(acc[2][i][j][3] + bvv);
                *(uint2*)(Vtb + (size_t)(b * DMODEL + oc) * S_LEN + sq) = *(uint2*)t4;
            }
        }
    }
}

// ---------------------------------------------------------------------------
// Kernel 2 (R16, kept): flash attention, q-tile 256 rows x 8 waves.
// R4 verified: dropped out of top-5 (<88 us).  K/V/P LDS is genuinely
// wave-shared (unlike qkv's x), so staging stays.
// ---------------------------------------------------------------------------
__global__ __launch_bounds__(512, 4) void flash_attn_mfma(
    const unsigned short* __restrict__ Qg,   // [B*S,1024] bf16, pre-scaled by CK
    const unsigned short* __restrict__ Kg,   // [B*S,1024] bf16
    const unsigned short* __restrict__ Vtg,  // [B,H,64,S] bf16
    unsigned short* __restrict__ ctxb)       // [B*S,1024] bf16
{
    __shared__ __align__(16) unsigned short Ks[16 * 512];  // 16 KB
    __shared__ __align__(16) unsigned short Vs[16 * 512];  // 16 KB
    __shared__ __align__(16) unsigned short Ps[16 * 512];  // 16 KB

    const int tid  = threadIdx.x;
    const int lane = tid & 63, w = tid >> 6;   // w 0..7
    const int quad = lane >> 4, l15 = lane & 15;

    // ---- XCD swizzle: 512 blocks; all 8 q-blocks of (b,h) on XCD bh%8 ----
    const int lin = blockIdx.x;            // 0..511
    const int xcd = lin & 7;
    const int s   = lin >> 3;              // 0..63
    const int bh  = xcd + 8 * (s >> 3);    // 0..63, bh%8 == xcd
    const int qblk = s & 7;                // 0..7
    const int b = bh >> 4, h = bh & 15;
    const int r0 = qblk * 256;

    bf16x8 qf[2][2];
    #pragma unroll
    for (int nt = 0; nt < 2; nt++)
        #pragma unroll
        for (int ds = 0; ds < 2; ds++)
            qf[nt][ds] = *(const bf16x8*)(Qg +
                (size_t)(b * S_LEN + r0 + w * 32 + nt * 16 + l15) * DMODEL +
                h * HD + ds * 32 + quad * 8);

    const int sw = w & 3;
    const unsigned short* gK = Kg +
        (size_t)(b * S_LEN + sw * 32 + l15) * DMODEL + h * HD + quad * 8;
    const unsigned short* gV = Vtg +
        ((size_t)(bh * HD + sw * 16 + l15)) * S_LEN + quad * 8;

    f32x4 O[2][4], lsum[2];
    #pragma unroll
    for (int rt = 0; rt < 2; rt++) {
        #pragma unroll
        for (int c = 0; c < 4; c++) lsum[rt][c] = 0.f;
        #pragma unroll
        for (int dt = 0; dt < 4; dt++)
            #pragma unroll
            for (int c = 0; c < 4; c++) O[rt][dt][c] = 0.f;
    }

    f32x4 zero4;
    #pragma unroll
    for (int c = 0; c < 4; c++) zero4[c] = 0.f;
    bf16x8 ones;
    #pragma unroll
    for (int c = 0; c < 8; c++) ones[c] = (short)0x3F80;   // bf16 1.0

    for (int st = 0; st < S_LEN / 128; st++) {
        __syncthreads();
        if (w < 4) {
            gld16(Ks + (w * 4 + 0) * 512, gK);
            gld16(Ks + (w * 4 + 1) * 512, gK + 32);
            gld16(Ks + (w * 4 + 2) * 512, gK + (size_t)16 * DMODEL);
            gld16(Ks + (w * 4 + 3) * 512, gK + (size_t)16 * DMODEL + 32);
            gK += (size_t)128 * DMODEL;
        } else {
            gld16(Vs + (sw * 4 + 0) * 512, gV);
            gld16(Vs + (sw * 4 + 1) * 512, gV + 32);
            gld16(Vs + (sw * 4 + 2) * 512, gV + 64);
            gld16(Vs + (sw * 4 + 3) * 512, gV + 96);
            gV += 128;
        }
        __syncthreads();

        #pragma unroll
        for (int r = 0; r < 4; r++) {
            f32x4 sc[2][2];
            {
                bf16x8 kf0 = *(const bf16x8*)&Ks[((r * 2 + 0) * 2 + 0) * 512 + lane * 8];
                bf16x8 kf1 = *(const bf16x8*)&Ks[((r * 2 + 1) * 2 + 0) * 512 + lane * 8];
                sc[0][0] = __builtin_amdgcn_mfma_f32_16x16x32_bf16(kf0, qf[0][0], zero4, 0, 0, 0);
                sc[0][1] = __builtin_amdgcn_mfma_f32_16x16x32_bf16(kf0, qf[1][0], zero4, 0, 0, 0);
                sc[1][0] = __builtin_amdgcn_mfma_f32_16x16x32_bf16(kf1, qf[0][0], zero4, 0, 0, 0);
                sc[1][1] = __builtin_amdgcn_mfma_f32_16x16x32_bf16(kf1, qf[1][0], zero4, 0, 0, 0);
                kf0 = *(const bf16x8*)&Ks[((r * 2 + 0) * 2 + 1) * 512 + lane * 8];
                kf1 = *(const bf16x8*)&Ks[((r * 2 + 1) * 2 + 1) * 512 + lane * 8];
                sc[0][0] = __builtin_amdgcn_mfma_f32_16x16x32_bf16(kf0, qf[0][1], sc[0][0], 0, 0, 0);
                sc[0][1] = __builtin_amdgcn_mfma_f32_16x16x32_bf16(kf0, qf[1][1], sc[0][1], 0, 0, 0);
                sc[1][0] = __builtin_amdgcn_mfma_f32_16x16x32_bf16(kf1, qf[0][1], sc[1][0], 0, 0, 0);
                sc[1][1] = __builtin_amdgcn_mfma_f32_16x16x32_bf16(kf1, qf[1][1], sc[1][1], 0, 0, 0);
            }

            #pragma unroll
            for (int nt = 0; nt < 2; nt++) {
                #pragma unroll
                for (int mt = 0; mt < 2; mt++) {
                    unsigned u[4];
                    #pragma unroll
                    for (int c = 0; c < 4; c++)
                        u[c] = __float_as_uint(__builtin_amdgcn_exp2f(sc[mt][nt][c]));
                    uint2 pk;
                    pk.x = __builtin_amdgcn_perm(u[1], u[0], 0x07060302u);
                    pk.y = __builtin_amdgcn_perm(u[3], u[2], 0x07060302u);
                    int off = (w * 2 + nt) * 512 + (mt * 2 + (quad >> 1)) * 128 +
                              l15 * 8 + (quad & 1) * 4;
                    *(uint2*)&Ps[off] = pk;
                }
            }

            bf16x8 pf0 = *(const bf16x8*)&Ps[(w * 2 + 0) * 512 + lane * 8];
            bf16x8 pf1 = *(const bf16x8*)&Ps[(w * 2 + 1) * 512 + lane * 8];
            lsum[0] = __builtin_amdgcn_mfma_f32_16x16x32_bf16(pf0, ones, lsum[0], 0, 0, 0);
            lsum[1] = __builtin_amdgcn_mfma_f32_16x16x32_bf16(pf1, ones, lsum[1], 0, 0, 0);
            #pragma unroll
            for (int dt = 0; dt < 4; dt++) {
                bf16x8 vf = *(const bf16x8*)&Vs[(dt * 4 + r) * 512 + lane * 8];
                O[0][dt] = __builtin_amdgcn_mfma_f32_16x16x32_bf16(pf0, vf, O[0][dt], 0, 0, 0);
                O[1][dt] = __builtin_amdgcn_mfma_f32_16x16x32_bf16(pf1, vf, O[1][dt], 0, 0, 0);
            }
        }
    }

    const size_t srow = (size_t)(b * S_LEN + r0 + w * 32);
    #pragma unroll
    for (int rt = 0; rt < 2; rt++) {
        #pragma unroll
        for (int reg = 0; reg < 4; reg++) {
            float li = 1.0f / lsum[rt][reg];
            size_t rowoff = (srow + rt * 16 + quad * 4 + reg) * DMODEL + h * HD + l15;
            #pragma unroll
            for (int dt = 0; dt < 4; dt++)
                ctxb[rowoff + dt * 16] = f2bf_rne(O[rt][dt][reg] * li);
        }
    }
}

// ---------------------------------------------------------------------------
// Kernel 3: output projection v4, 8-way K-split.  512 blocks x 512 thr.
// ---------------------------------------------------------------------------
__global__ __launch_bounds__(512) void out_proj_mfma(
    const unsigned short* __restrict__ ctxb,
    const unsigned short* __restrict__ WfT,
    const float* __restrict__ bfb,
    float* __restrict__ out)
{
    __shared__ float Red[8 * 1024];   // [wave][lane][j*4+reg], 32 KB

    const int tid = threadIdx.x;
    const int lane = tid & 63, w = tid >> 6;    // w 0..7
    const int quad = lane >> 4, l15 = lane & 15;
    const int m0 = blockIdx.x * 16;

    const unsigned short* pA = ctxb + (size_t)(m0 + l15) * DMODEL + w * 128 + quad * 8;
    const unsigned short* pB = WfT + (size_t)l15 * DMODEL + w * 128 + quad * 8;

    f32x4 acc[4];
    #pragma unroll
    for (int j = 0; j < 4; j++)
        #pragma unroll
        for (int c = 0; c < 4; c++) acc[j][c] = 0.f;

    #pragma unroll
    for (int k0 = 0; k0 < 128; k0 += 32) {
        bf16x8 af = *(const bf16x8*)(pA + k0);
        #pragma unroll
        for (int j = 0; j < 4; j++) {
            bf16x8 bfr = *(const bf16x8*)(pB + (size_t)j * 16 * DMODEL + k0);
            acc[j] = __builtin_amdgcn_mfma_f32_16x16x32_bf16(af, bfr, acc[j], 0, 0, 0);
        }
    }

    #pragma unroll
    for (int j = 0; j < 4; j++)
        #pragma unroll
        for (int reg = 0; reg < 4; reg++)
            Red[w * 1024 + lane * 16 + j * 4 + reg] = acc[j][reg];
    __syncthreads();

    const int row = tid >> 5;          // 0..15
    const int c0  = (tid & 31) * 2;    // 0..62
    float2 o;
    float* op = &o.x;
    #pragma unroll
    for (int cc = 0; cc < 2; cc++) {
        int col = c0 + cc;
        int idx = ((row >> 2) * 16 + (col & 15)) * 16 + (col >> 4) * 4 + (row & 3);
        float s = 0.f;
        #pragma unroll
        for (int wv = 0; wv < 8; wv++) s += Red[wv * 1024 + idx];
        op[cc] = s + bfb[col];
    }
    *(float2*)(out + (size_t)(m0 + row) * HD + c0) = o;
}

// ---------------------------------------------------------------------------
extern "C" void kernel_launch(void* const* d_in, const int* in_sizes, int n_in,
                              void* d_out, int out_size, void* d_ws, size_t ws_size,
                              hipStream_t stream)
{
    (void)in_sizes; (void)n_in; (void)out_size; (void)ws_size;
    const float* x  = (const float*)d_in[0];
    const float* Wq = (const float*)d_in[1];
    const float* bq = (const float*)d_in[2];
    const float* Wk = (const float*)d_in[3];
    const float* bk = (const float*)d_in[4];
    const float* Wv = (const float*)d_in[5];
    const float* bv = (const float*)d_in[6];
    const float* Wf = (const float*)d_in[7];
    const float* bf = (const float*)d_in[8];
    float* out = (float*)d_out;

    char* wsb = (char*)d_ws;
    unsigned short* xb   = (unsigned short*)wsb;            // 16 MB, dead after qkv
    unsigned short* ctxb = (unsigned short*)wsb;            // reuses xb region
    unsigned short* WT   = xb + (size_t)M_TOT * DMODEL;     // 3x2 MB + WfT
    unsigned short* WfT  = WT + (size_t)3 * DMODEL * DMODEL;
    unsigned short* Qb   = (unsigned short*)(wsb + (size_t)32 * 1024 * 1024);
    unsigned short* Kb   = Qb + (size_t)M_TOT * DMODEL;
    unsigned short* Vtb  = Kb + (size_t)M_TOT * DMODEL;

    cvt_fused<<<dim3(16, 16, 5), 256, 0, stream>>>(x, Wq, Wk, Wv, Wf, xb, WT);
    qkv_fused_mfma<<<dim3(512), 512, 0, stream>>>(xb, WT, bq, bk, bv, Qb, Kb, Vtb);
    flash_attn_mfma<<<dim3(512), 512, 0, stream>>>(Qb, Kb, Vtb, ctxb);
    out_proj_mfma<<<dim3(M_TOT / 16), 512, 0, stream>>>(ctxb, WfT, bf, out);
}